// Round 9
// baseline (576.791 us; speedup 1.0000x reference)
//
#include <hip/hip_runtime.h>

// B=64, IN=1024, OUT=1024, T=256
// syn[b,o,t] = sum_i W[o,i]*x[b,i,t]; spikes via f64 LIF scan.
//
// R9: Ozaki int8, 6 truncated 7-bit digits, pair cutoff p+q<=5 (21 MFMAs/ksl,
// was 26 — dropped p+q=6 terms ~1e-13/syn, 30x below truncation residual).
// Fragment-ordered wsl/xsl (R8: zero bank conflicts). __launch_bounds__(256,3):
// 48 KB LDS -> 3 blocks/CU, 3 waves/SIMD to hide staging under MFMA
// (R8 capped at 2 -> 165 us structural idle).
// D-placement decoded by runtime probes. Fallback: R6 f64-MFMA path.

#define B_DIM 64
#define IN_DIM 1024
#define OUT_DIM 1024
#define T_DIM 256

typedef int v4i __attribute__((ext_vector_type(4)));
typedef int v16i __attribute__((ext_vector_type(16)));
typedef double v4d __attribute__((ext_vector_type(4)));

// ---------------- workspace layout (bytes) ----------------
#define LO_OFF   0ull                    // 67108864  f32 syn_lo
#define WSL_OFF  67108864ull             // 6291456   i8 W frags [6][o32:32][ks:32][lane:64][16]
#define XSL_OFF  73400320ull             // 100663296 i8 x frags [6][b:64][t32:8][ks:32][lane:64][16]
#define AL_OFF   174063616ull            // 4096      i32 alpha_e[1024]
#define BE_OFF   174067712ull            // 65536     i32 beta_e[64][256]
#define PART_OFF 174133248ull            // 1048576   f32 partial maxes [64][16][256]
#define WS_NEED  175181824ull

// ---------------- K1a: partial column maxes (proven) ----------------
__global__ __launch_bounds__(256) void k_beta_part(const float* __restrict__ x,
                                                   float* __restrict__ part)
{
    const int ic = blockIdx.x;   // i chunk 0..15
    const int b  = blockIdx.y;
    const int t  = threadIdx.x;
    const float* p = x + ((size_t)b * IN_DIM + ic * 64) * T_DIM + t;
    float m = 0.f;
    #pragma unroll 4
    for (int i = 0; i < 64; ++i) m = fmaxf(m, fabsf(p[(size_t)i * T_DIM]));
    part[((size_t)b * 16 + ic) * T_DIM + t] = m;
}

// ---------------- K1b: beta exponents (proven) ----------------
__global__ __launch_bounds__(256) void k_beta(const float* __restrict__ part,
                                              int* __restrict__ beta_e)
{
    const int b = blockIdx.x, t = threadIdx.x;
    float m = 0.f;
    #pragma unroll
    for (int ic = 0; ic < 16; ++ic)
        m = fmaxf(m, part[((size_t)b * 16 + ic) * T_DIM + t]);
    int e = 0;
    if (m > 0.f) frexpf(m, &e);   // |x|/2^e < 1
    beta_e[b * T_DIM + t] = e;
}

// ---------------- K2: slice x -> fragment order (proven R8) ----------------
__global__ __launch_bounds__(256) void k_slice_x(const float* __restrict__ x,
    const int* __restrict__ beta_e, signed char* __restrict__ xsl)
{
    __shared__ float ft[64][65];
    const int tb = blockIdx.x;    // 0..3
    const int ib = blockIdx.y;    // 0..15
    const int b  = blockIdx.z;
    const int tid = threadIdx.x;
    const int t0 = tb * 64, i0 = ib * 64;
    #pragma unroll
    for (int p = 0; p < 16; ++p) {
        int id = tid + p * 256;
        int il = id >> 6, tl = id & 63;
        ft[il][tl] = x[((size_t)b * IN_DIM + i0 + il) * T_DIM + t0 + tl];
    }
    __syncthreads();

    const int t32l = tid >> 7;
    const int ksl  = (tid >> 6) & 1;
    const int lane = tid & 63;
    const int t_local = t32l * 32 + (lane & 31);
    const int k_local = ksl * 32 + (lane >> 5) * 16;
    const int e = beta_e[b * T_DIM + t0 + t_local];

    signed char dig[16][6];
    #pragma unroll
    for (int j = 0; j < 16; ++j) {
        double r = ldexp((double)ft[k_local + j][t_local], -e);  // exact dyadic
        #pragma unroll
        for (int p = 0; p < 6; ++p) {
            r *= 128.0;              // exact
            double d = trunc(r);     // digit in [-127,127]
            r -= d;                  // exact
            dig[j][p] = (signed char)(int)d;
        }
    }
    #pragma unroll
    for (int p = 0; p < 6; ++p) {
        int w[4];
        #pragma unroll
        for (int g = 0; g < 4; ++g)
            w[g] = (dig[4*g][p] & 0xff) | ((dig[4*g+1][p] & 0xff) << 8) |
                   ((dig[4*g+2][p] & 0xff) << 16) | ((dig[4*g+3][p] & 0xff) << 24);
        const size_t base =
            ((((size_t)p * B_DIM + b) * 8 + (tb * 2 + t32l)) * 32 + (ib * 2 + ksl)) * 1024
            + lane * 16;
        *(v4i*)&xsl[base] = (v4i){w[0], w[1], w[2], w[3]};
    }
}

// ---------------- K3: alpha + slice W -> fragment order (proven R8) --------
__global__ __launch_bounds__(256) void k_slice_w(const float* __restrict__ W,
    signed char* __restrict__ wsl, int* __restrict__ alpha_e)
{
    __shared__ float red[256];
    __shared__ float wrow[1024];
    __shared__ int se;
    const int o = blockIdx.x, tid = threadIdx.x;
    float4 v = *(const float4*)&W[(size_t)o * IN_DIM + tid * 4];
    *(float4*)&wrow[tid * 4] = v;
    float m = fmaxf(fmaxf(fabsf(v.x), fabsf(v.y)), fmaxf(fabsf(v.z), fabsf(v.w)));
    red[tid] = m; __syncthreads();
    for (int s = 128; s > 0; s >>= 1) {
        if (tid < s) red[tid] = fmaxf(red[tid], red[tid + s]);
        __syncthreads();
    }
    if (tid == 0) { int e = 0; if (red[0] > 0.f) frexpf(red[0], &e); se = e; alpha_e[o] = e; }
    __syncthreads();
    if (tid >= 64) return;
    const int e = se;
    const int ks = tid >> 1, khalf = tid & 1;
    const int k0 = tid * 16;
    const int lane = (o & 31) + 32 * khalf;

    signed char dig[16][6];
    #pragma unroll
    for (int j = 0; j < 16; ++j) {
        double r = ldexp((double)wrow[k0 + j], -e);
        #pragma unroll
        for (int p = 0; p < 6; ++p) {
            r *= 128.0; double d = trunc(r); r -= d;
            dig[j][p] = (signed char)(int)d;
        }
    }
    #pragma unroll
    for (int p = 0; p < 6; ++p) {
        int w[4];
        #pragma unroll
        for (int g = 0; g < 4; ++g)
            w[g] = (dig[4*g][p] & 0xff) | ((dig[4*g+1][p] & 0xff) << 8) |
                   ((dig[4*g+2][p] & 0xff) << 16) | ((dig[4*g+3][p] & 0xff) << 24);
        const size_t base =
            (((size_t)p * 32 + (o >> 5)) * 32 + ks) * 1024 + lane * 16;
        *(v4i*)&wsl[base] = (v4i){w[0], w[1], w[2], w[3]};
    }
}

// ---------------- K4: Ozaki i8 MFMA GEMM (fragment-ordered) ----------------
// Block 64(o)x64(t), 4 waves 2x2 of 32x32. BK=64 (2 MFMA k-steps).
// LDS: [p:6][half32:2][ksl:2][lane:64][16B] per matrix = 24 KB each.
// 3 blocks/CU (48 KB LDS), pair cutoff p+q<=5 -> 21 MFMAs/ksl.
__global__ __launch_bounds__(256, 3) void k_oz_gemm(
    const signed char* __restrict__ wsl, const signed char* __restrict__ xsl,
    const int* __restrict__ alpha_e, const int* __restrict__ beta_e,
    float* __restrict__ syn_hi, float* __restrict__ syn_lo)
{
    __shared__ __align__(16) signed char As[24576];
    __shared__ __align__(16) signed char Bs[24576];

    const int tid = threadIdx.x;
    const int lane = tid & 63, wave = tid >> 6;
    const int tb = blockIdx.x;   // 0..3
    const int ob = blockIdx.y;   // 0..15
    const int b  = blockIdx.z;
    const int o0 = ob * 64, t0 = tb * 64;
    const int woh = wave >> 1;   // o half (0/1)
    const int wth = wave & 1;    // t half (0/1)

    v16i acc[6];
    #pragma unroll
    for (int s = 0; s < 6; ++s)
        acc[s] = (v16i){0,0,0,0,0,0,0,0,0,0,0,0,0,0,0,0};

    const int sh  = (tid >> 7) & 1;
    const int sks = (tid >> 6) & 1;
    const size_t abase = (((size_t)(2 * ob + sh)) * 32 + sks) * 1024 + (tid & 63) * 16;
    const size_t bbase = ((((size_t)b) * 8 + (2 * tb + sh)) * 32 + sks) * 1024 + (tid & 63) * 16;
    const int ldso = tid * 16;

    v4i pa[6], pb[6];
    #pragma unroll
    for (int j = 0; j < 6; ++j) {   // preload kt=0
        pa[j] = *(const v4i*)(wsl + ((size_t)j << 20) + abase);
        pb[j] = *(const v4i*)(xsl + ((size_t)j << 24) + bbase);
    }

    for (int kt = 0; kt < 16; ++kt) {
        #pragma unroll
        for (int j = 0; j < 6; ++j) {
            *(v4i*)(As + j * 4096 + ldso) = pa[j];
            *(v4i*)(Bs + j * 4096 + ldso) = pb[j];
        }
        if (kt < 15) {
            #pragma unroll
            for (int j = 0; j < 6; ++j) {
                pa[j] = *(const v4i*)(wsl + ((size_t)j << 20) + abase + (kt + 1) * 2048);
                pb[j] = *(const v4i*)(xsl + ((size_t)j << 24) + bbase + (kt + 1) * 2048);
            }
        }
        __syncthreads();

        #pragma unroll
        for (int ksl = 0; ksl < 2; ++ksl) {
            const int fro = woh * 2048 + ksl * 1024 + lane * 16;
            const int frt = wth * 2048 + ksl * 1024 + lane * 16;
            v4i bf[6];
            #pragma unroll
            for (int q = 0; q < 6; ++q)
                bf[q] = *(const v4i*)(Bs + q * 4096 + frt);
            #pragma unroll
            for (int p = 0; p < 6; ++p) {
                v4i af = *(const v4i*)(As + p * 4096 + fro);
                #pragma unroll
                for (int q = 0; q < 6; ++q) {
                    if (p + q <= 5)
                        acc[p + q] = __builtin_amdgcn_mfma_i32_32x32x32_i8(
                            af, bf[q], acc[p + q], 0, 0, 0);
                }
            }
        }
        __syncthreads();
    }

    // Runtime D-placement probes (R6/R7 technique).
    const int lr = lane & 31;
    const int rv = (lr + 1) * 0x01010101;
    const v4i pav  = {rv, rv, rv, rv};
    const v4i onev = {0x01010101, 0x01010101, 0x01010101, 0x01010101};
    const v16i z = (v16i){0,0,0,0,0,0,0,0,0,0,0,0,0,0,0,0};
    v16i d1 = __builtin_amdgcn_mfma_i32_32x32x32_i8(pav, onev, z, 0, 0, 0);
    v16i d2 = __builtin_amdgcn_mfma_i32_32x32x32_i8(onev, pav, z, 0, 0, 0);

    const int col = (d2[0] >> 5) - 1;            // 0..31 within tile
    const int gt = t0 + wth * 32 + col;
    const int eb = beta_e[b * T_DIM + gt];
    float* ohi = syn_hi + ((size_t)b * OUT_DIM + o0) * T_DIM + gt;
    float* olo = syn_lo + ((size_t)b * OUT_DIM + o0) * T_DIM + gt;

    const double C0 = 0x1p-14, C1 = 0x1p-21, C2 = 0x1p-28, C3 = 0x1p-35,
                 C4 = 0x1p-42, C5 = 0x1p-49;
    #pragma unroll
    for (int r = 0; r < 16; ++r) {
        const int row = (d1[r] >> 5) - 1;        // 0..31 within tile
        const int go = woh * 32 + row;
        const int ea = alpha_e[o0 + go];
        double v = (double)acc[0][r] * C0 + (double)acc[1][r] * C1 +
                   (double)acc[2][r] * C2 + (double)acc[3][r] * C3 +
                   (double)acc[4][r] * C4 + (double)acc[5][r] * C5;
        double syn = ldexp(v, ea + eb);
        float hi = (float)syn;
        float lo = (float)(syn - (double)hi);
        ohi[(size_t)go * T_DIM] = hi;
        olo[(size_t)go * T_DIM] = lo;
    }
}

// ---------------- Fallback GEMM: R6 f64-MFMA with probes (proven) ----------
#define BM 128
#define BN 128
#define BK 16
#define LDA 130

__global__ __launch_bounds__(256, 2) void spk_gemm_mfma64p_kernel(
    const float* __restrict__ x, const float* __restrict__ W,
    float* __restrict__ syn_hi, float* __restrict__ syn_lo)
{
    const int tid  = threadIdx.x;
    const int lane = tid & 63;
    const int wave = tid >> 6;
    const int tb = blockIdx.x, ob = blockIdx.y, b = blockIdx.z;

    __shared__ __align__(16) double As[BK][LDA];
    __shared__ __align__(16) double Bs[BK][LDA];

    const v4d zz = {0.0, 0.0, 0.0, 0.0};
    v4d d1 = __builtin_amdgcn_mfma_f64_16x16x4f64((double)lane, 1.0, zz, 0, 0, 0);
    v4d d2 = __builtin_amdgcn_mfma_f64_16x16x4f64(1.0, (double)lane, zz, 0, 0, 0);
    const bool a_h1 = (((int)d1[0] & 3) == 0);
    const bool b_h1 = (((int)d2[0] & 3) == 0);
    int drow[4];
    #pragma unroll
    for (int r = 0; r < 4; ++r) {
        const int v = (int)d1[r];
        drow[r] = (a_h1 ? (v - 96) >> 2 : (v - 6) >> 4) & 15;
    }
    const int am = a_h1 ? (lane & 15) : (lane >> 2);
    const int ak = a_h1 ? (lane >> 4) : (lane & 3);
    const int bn = b_h1 ? (lane & 15) : (lane >> 2);
    const int bk = b_h1 ? (lane >> 4) : (lane & 3);
    const int dcol = lane & 15;

    const int o0 = ob * BM, t0 = tb * BN;
    const float* Wp = W + (size_t)o0 * IN_DIM;
    const float* xp = x + (size_t)b * IN_DIM * T_DIM + t0;
    const int wo = (wave >> 1) * 64, wt = (wave & 1) * 64;

    v4d acc[4][4];
    #pragma unroll
    for (int i = 0; i < 4; ++i)
        #pragma unroll
        for (int j = 0; j < 4; ++j) acc[i][j] = zz;

    const int ar0 = tid / 4, ac = (tid % 4) * 4;
    const int bkr0 = tid / 32, btc = (tid % 32) * 4;

    float4 pa[2], pb[2];
    #pragma unroll
    for (int p = 0; p < 2; ++p) {
        pa[p] = *(const float4*)&Wp[(size_t)(ar0 + p * 64) * IN_DIM + ac];
        pb[p] = *(const float4*)&xp[(size_t)(bkr0 + p * 8) * T_DIM + btc];
    }

    for (int k0 = 0; k0 < IN_DIM; k0 += BK) {
        #pragma unroll
        for (int p = 0; p < 2; ++p) {
            const int r = ar0 + p * 64;
            As[ac + 0][r] = (double)pa[p].x; As[ac + 1][r] = (double)pa[p].y;
            As[ac + 2][r] = (double)pa[p].z; As[ac + 3][r] = (double)pa[p].w;
            const int kr = bkr0 + p * 8;
            Bs[kr][btc + 0] = (double)pb[p].x; Bs[kr][btc + 1] = (double)pb[p].y;
            Bs[kr][btc + 2] = (double)pb[p].z; Bs[kr][btc + 3] = (double)pb[p].w;
        }
        if (k0 + BK < IN_DIM) {
            #pragma unroll
            for (int p = 0; p < 2; ++p) {
                pa[p] = *(const float4*)&Wp[(size_t)(ar0 + p * 64) * IN_DIM + k0 + BK + ac];
                pb[p] = *(const float4*)&xp[(size_t)(bkr0 + p * 8 + k0 + BK) * T_DIM + btc];
            }
        }
        __syncthreads();
        #pragma unroll
        for (int kk = 0; kk < 4; ++kk) {
            const int kra = kk * 4 + ak, krb = kk * 4 + bk;
            double a[4], bb[4];
            #pragma unroll
            for (int i = 0; i < 4; ++i) a[i] = As[kra][wo + i * 16 + am];
            #pragma unroll
            for (int j = 0; j < 4; ++j) bb[j] = Bs[krb][wt + j * 16 + bn];
            #pragma unroll
            for (int i = 0; i < 4; ++i)
                #pragma unroll
                for (int j = 0; j < 4; ++j)
                    acc[i][j] = __builtin_amdgcn_mfma_f64_16x16x4f64(a[i], bb[j], acc[i][j], 0, 0, 0);
        }
        __syncthreads();
    }

    float* ohi = syn_hi + ((size_t)b * OUT_DIM + o0) * T_DIM + t0;
    float* olo = syn_lo + ((size_t)b * OUT_DIM + o0) * T_DIM + t0;
    #pragma unroll
    for (int i = 0; i < 4; ++i)
        #pragma unroll
        for (int j = 0; j < 4; ++j) {
            const int col = wt + j * 16 + dcol;
            #pragma unroll
            for (int r = 0; r < 4; ++r) {
                double s = acc[i][j][r];
                float hi = (float)s;
                float lo = (float)(s - (double)hi);
                const size_t off = (size_t)(wo + i * 16 + drow[r]) * T_DIM + col;
                ohi[off] = hi; olo[off] = lo;
            }
        }
}

// ---------------- scan: f64 LIF, in place over hi (proven) ----------------
__global__ __launch_bounds__(256) void spk_scan_f64_kernel(
    float* __restrict__ hi, const float* __restrict__ lo)
{
    const int TC = 16;
    __shared__ float thi[256][TC + 1];
    __shared__ float tlo[256][TC + 1];
    const int tid = threadIdx.x;
    const size_t row0 = (size_t)blockIdx.x * 256;

    double mem = 0.0;
    for (int t0 = 0; t0 < T_DIM; t0 += TC) {
        #pragma unroll
        for (int p = 0; p < 4; ++p) {
            int id = tid + p * 256;
            int r = id / 4, c = (id % 4) * 4;
            size_t g = (row0 + r) * T_DIM + t0 + c;
            float4 vh = *(const float4*)&hi[g];
            thi[r][c] = vh.x; thi[r][c+1] = vh.y; thi[r][c+2] = vh.z; thi[r][c+3] = vh.w;
            float4 vl = *(const float4*)&lo[g];
            tlo[r][c] = vl.x; tlo[r][c+1] = vl.y; tlo[r][c+2] = vl.z; tlo[r][c+3] = vl.w;
        }
        __syncthreads();
        float spk[TC];
        #pragma unroll
        for (int t = 0; t < TC; ++t) {
            double s = (double)thi[tid][t] + (double)tlo[tid][t];
            double reset = (mem > 1.0) ? 1.0 : 0.0;
            mem = 0.9 * mem + s - reset;
            spk[t] = ((mem - 1.0) > 0.0) ? 1.0f : 0.0f;
        }
        __syncthreads();
        #pragma unroll
        for (int t = 0; t < TC; ++t) thi[tid][t] = spk[t];
        __syncthreads();
        #pragma unroll
        for (int p = 0; p < 4; ++p) {
            int id = tid + p * 256;
            int r = id / 4, c = (id % 4) * 4;
            float4 v = make_float4(thi[r][c], thi[r][c+1], thi[r][c+2], thi[r][c+3]);
            *(float4*)&hi[(row0 + r) * T_DIM + t0 + c] = v;
        }
        __syncthreads();
    }
}

extern "C" void kernel_launch(void* const* d_in, const int* in_sizes, int n_in,
                              void* d_out, int out_size, void* d_ws, size_t ws_size,
                              hipStream_t stream)
{
    const float* x = (const float*)d_in[0];
    const float* W = (const float*)d_in[1];
    float* hi = (float*)d_out;
    char* ws = (char*)d_ws;
    float* lo = (float*)(ws + LO_OFF);

    if (ws_size >= WS_NEED) {
        signed char* wsl = (signed char*)(ws + WSL_OFF);
        signed char* xsl = (signed char*)(ws + XSL_OFF);
        int* alpha = (int*)(ws + AL_OFF);
        int* beta  = (int*)(ws + BE_OFF);
        float* part = (float*)(ws + PART_OFF);

        k_beta_part<<<dim3(16, B_DIM), dim3(256), 0, stream>>>(x, part);
        k_beta<<<dim3(B_DIM), dim3(256), 0, stream>>>(part, beta);
        k_slice_w<<<dim3(OUT_DIM), dim3(256), 0, stream>>>(W, wsl, alpha);
        k_slice_x<<<dim3(4, 16, B_DIM), dim3(256), 0, stream>>>(x, beta, xsl);
        k_oz_gemm<<<dim3(4, 16, B_DIM), dim3(256), 0, stream>>>(wsl, xsl, alpha, beta, hi, lo);
    } else {
        spk_gemm_mfma64p_kernel<<<dim3(2, 8, B_DIM), dim3(256), 0, stream>>>(x, W, hi, lo);
    }
    spk_scan_f64_kernel<<<dim3((B_DIM * OUT_DIM) / 256), dim3(256), 0, stream>>>(hi, lo);
}

// Round 10
// 510.198 us; speedup vs baseline: 1.1305x; 1.1305x over previous
//
#include <hip/hip_runtime.h>

// B=64, IN=1024, OUT=1024, T=256
// syn[b,o,t] = sum_i W[o,i]*x[b,i,t]; spikes via f64 LIF scan.
//
// R10: Ozaki int8 (6 digits, p+q<=5 -> 21 MFMAs/kstep; numerics proven R9).
// GEMM: global_load_lds (16B DMA) + BK=32 double buffer, 1 barrier/kstep.
// No prefetch VGPRs -> acc(96)+arch fits 3 waves/SIMD (R9 spilled: 645 MB
// scratch writes at (256,3) with register prefetch). LDS 2x24KB=48KB,
// 3 blocks/CU. Fragment-ordered wsl/xsl (R8: zero bank conflicts), DMA dest
// = wave-uniform base + lane*16 (m104 constraint satisfied by layout).
// D-placement decoded by runtime probes. Fallback: R6 f64-MFMA path.

#define B_DIM 64
#define IN_DIM 1024
#define OUT_DIM 1024
#define T_DIM 256

typedef int v4i __attribute__((ext_vector_type(4)));
typedef int v16i __attribute__((ext_vector_type(16)));
typedef double v4d __attribute__((ext_vector_type(4)));

// ---------------- workspace layout (bytes) ----------------
#define LO_OFF   0ull                    // 67108864  f32 syn_lo
#define WSL_OFF  67108864ull             // 6291456   i8 W frags [6][o32:32][ks:32][lane:64][16]
#define XSL_OFF  73400320ull             // 100663296 i8 x frags [6][b:64][t32:8][ks:32][lane:64][16]
#define AL_OFF   174063616ull            // 4096      i32 alpha_e[1024]
#define BE_OFF   174067712ull            // 65536     i32 beta_e[64][256]
#define PART_OFF 174133248ull            // 1048576   f32 partial maxes [64][16][256]
#define WS_NEED  175181824ull

__device__ __forceinline__ void gload_lds16(const void* g, void* l)
{
    __builtin_amdgcn_global_load_lds(
        (const __attribute__((address_space(1))) void*)g,
        (__attribute__((address_space(3))) void*)l, 16, 0, 0);
}

// ---------------- K1a: partial column maxes (proven) ----------------
__global__ __launch_bounds__(256) void k_beta_part(const float* __restrict__ x,
                                                   float* __restrict__ part)
{
    const int ic = blockIdx.x;   // i chunk 0..15
    const int b  = blockIdx.y;
    const int t  = threadIdx.x;
    const float* p = x + ((size_t)b * IN_DIM + ic * 64) * T_DIM + t;
    float m = 0.f;
    #pragma unroll 4
    for (int i = 0; i < 64; ++i) m = fmaxf(m, fabsf(p[(size_t)i * T_DIM]));
    part[((size_t)b * 16 + ic) * T_DIM + t] = m;
}

// ---------------- K1b: beta exponents (proven) ----------------
__global__ __launch_bounds__(256) void k_beta(const float* __restrict__ part,
                                              int* __restrict__ beta_e)
{
    const int b = blockIdx.x, t = threadIdx.x;
    float m = 0.f;
    #pragma unroll
    for (int ic = 0; ic < 16; ++ic)
        m = fmaxf(m, part[((size_t)b * 16 + ic) * T_DIM + t]);
    int e = 0;
    if (m > 0.f) frexpf(m, &e);   // |x|/2^e < 1
    beta_e[b * T_DIM + t] = e;
}

// ---------------- K2: slice x -> fragment order (proven R8) ----------------
__global__ __launch_bounds__(256) void k_slice_x(const float* __restrict__ x,
    const int* __restrict__ beta_e, signed char* __restrict__ xsl)
{
    __shared__ float ft[64][65];
    const int tb = blockIdx.x;    // 0..3
    const int ib = blockIdx.y;    // 0..15
    const int b  = blockIdx.z;
    const int tid = threadIdx.x;
    const int t0 = tb * 64, i0 = ib * 64;
    #pragma unroll
    for (int p = 0; p < 16; ++p) {
        int id = tid + p * 256;
        int il = id >> 6, tl = id & 63;
        ft[il][tl] = x[((size_t)b * IN_DIM + i0 + il) * T_DIM + t0 + tl];
    }
    __syncthreads();

    const int t32l = tid >> 7;
    const int ksl  = (tid >> 6) & 1;
    const int lane = tid & 63;
    const int t_local = t32l * 32 + (lane & 31);
    const int k_local = ksl * 32 + (lane >> 5) * 16;
    const int e = beta_e[b * T_DIM + t0 + t_local];

    signed char dig[16][6];
    #pragma unroll
    for (int j = 0; j < 16; ++j) {
        double r = ldexp((double)ft[k_local + j][t_local], -e);  // exact dyadic
        #pragma unroll
        for (int p = 0; p < 6; ++p) {
            r *= 128.0;              // exact
            double d = trunc(r);     // digit in [-127,127]
            r -= d;                  // exact
            dig[j][p] = (signed char)(int)d;
        }
    }
    #pragma unroll
    for (int p = 0; p < 6; ++p) {
        int w[4];
        #pragma unroll
        for (int g = 0; g < 4; ++g)
            w[g] = (dig[4*g][p] & 0xff) | ((dig[4*g+1][p] & 0xff) << 8) |
                   ((dig[4*g+2][p] & 0xff) << 16) | ((dig[4*g+3][p] & 0xff) << 24);
        const size_t base =
            ((((size_t)p * B_DIM + b) * 8 + (tb * 2 + t32l)) * 32 + (ib * 2 + ksl)) * 1024
            + lane * 16;
        *(v4i*)&xsl[base] = (v4i){w[0], w[1], w[2], w[3]};
    }
}

// ---------------- K3: alpha + slice W -> fragment order (proven R8) --------
__global__ __launch_bounds__(256) void k_slice_w(const float* __restrict__ W,
    signed char* __restrict__ wsl, int* __restrict__ alpha_e)
{
    __shared__ float red[256];
    __shared__ float wrow[1024];
    __shared__ int se;
    const int o = blockIdx.x, tid = threadIdx.x;
    float4 v = *(const float4*)&W[(size_t)o * IN_DIM + tid * 4];
    *(float4*)&wrow[tid * 4] = v;
    float m = fmaxf(fmaxf(fabsf(v.x), fabsf(v.y)), fmaxf(fabsf(v.z), fabsf(v.w)));
    red[tid] = m; __syncthreads();
    for (int s = 128; s > 0; s >>= 1) {
        if (tid < s) red[tid] = fmaxf(red[tid], red[tid + s]);
        __syncthreads();
    }
    if (tid == 0) { int e = 0; if (red[0] > 0.f) frexpf(red[0], &e); se = e; alpha_e[o] = e; }
    __syncthreads();
    if (tid >= 64) return;
    const int e = se;
    const int ks = tid >> 1, khalf = tid & 1;
    const int k0 = tid * 16;
    const int lane = (o & 31) + 32 * khalf;

    signed char dig[16][6];
    #pragma unroll
    for (int j = 0; j < 16; ++j) {
        double r = ldexp((double)wrow[k0 + j], -e);
        #pragma unroll
        for (int p = 0; p < 6; ++p) {
            r *= 128.0; double d = trunc(r); r -= d;
            dig[j][p] = (signed char)(int)d;
        }
    }
    #pragma unroll
    for (int p = 0; p < 6; ++p) {
        int w[4];
        #pragma unroll
        for (int g = 0; g < 4; ++g)
            w[g] = (dig[4*g][p] & 0xff) | ((dig[4*g+1][p] & 0xff) << 8) |
                   ((dig[4*g+2][p] & 0xff) << 16) | ((dig[4*g+3][p] & 0xff) << 24);
        const size_t base =
            (((size_t)p * 32 + (o >> 5)) * 32 + ks) * 1024 + lane * 16;
        *(v4i*)&wsl[base] = (v4i){w[0], w[1], w[2], w[3]};
    }
}

// ---------------- K4: Ozaki i8 MFMA GEMM (DMA + double buffer) -------------
// Block 64(o)x64(t), 4 waves 2x2 of 32x32. BK=32 (one MFMA k-step), 32 steps.
// Buffer: A [p:6][h:2][lane:64][16] = 12 KB at 0; B same at 12288. x2 buffers.
__global__ __launch_bounds__(256, 3) void k_oz_gemm(
    const signed char* __restrict__ wsl, const signed char* __restrict__ xsl,
    const int* __restrict__ alpha_e, const int* __restrict__ beta_e,
    float* __restrict__ syn_hi, float* __restrict__ syn_lo)
{
    __shared__ __align__(16) signed char LB[2][24576];

    const int tid = threadIdx.x;
    const int lane = tid & 63, wave = tid >> 6;
    const int tb = blockIdx.x;   // 0..3
    const int ob = blockIdx.y;   // 0..15
    const int b  = blockIdx.z;
    const int o0 = ob * 64, t0 = tb * 64;
    const int woh = wave >> 1;   // o half (0/1)
    const int wth = wave & 1;    // t half (0/1)

    v16i acc[6];
    #pragma unroll
    for (int s = 0; s < 6; ++s)
        acc[s] = (v16i){0,0,0,0,0,0,0,0,0,0,0,0,0,0,0,0};

    // Staging: unit u = 256*j + tid (j=0..5). j<3 -> A slice 2j+sh2, half sks;
    // j>=3 -> B slice 2(j-3)+sh2, half sks. LDS off u*16; DMA base uniform/wave.
    const int sh2 = (tid >> 7) & 1;
    const int sks = (tid >> 6) & 1;
    const int l16 = (tid & 63) * 16;

    const signed char* aG[3];
    const signed char* bG[3];
    #pragma unroll
    for (int j = 0; j < 3; ++j) {
        aG[j] = wsl + ((size_t)(2 * j + sh2) << 20)
                    + ((size_t)(2 * ob + sks) << 15) + l16;
        bG[j] = xsl + ((size_t)(2 * j + sh2) << 24) + ((size_t)b << 18)
                    + ((size_t)(2 * tb + sks) << 15) + l16;
    }
    const int aL = wave * 1024;          // + j*4096 (+ buffer base)
    const int bL = 12288 + wave * 1024;

    // prologue: kt=0 into LB[0]
    #pragma unroll
    for (int j = 0; j < 3; ++j) {
        gload_lds16(aG[j], &LB[0][j * 4096 + aL]);
        gload_lds16(bG[j], &LB[0][j * 4096 + bL]);
        aG[j] += 1024; bG[j] += 1024;
    }
    __syncthreads();

    for (int kt = 0; kt < 32; ++kt) {
        const int cur = kt & 1;
        if (kt < 31) {
            #pragma unroll
            for (int j = 0; j < 3; ++j) {
                gload_lds16(aG[j], &LB[cur ^ 1][j * 4096 + aL]);
                gload_lds16(bG[j], &LB[cur ^ 1][j * 4096 + bL]);
                aG[j] += 1024; bG[j] += 1024;
            }
        }
        const signed char* base = LB[cur];
        v4i bf[6];
        #pragma unroll
        for (int q = 0; q < 6; ++q)
            bf[q] = *(const v4i*)(base + 12288 + q * 2048 + wth * 1024 + l16 - (sks ? 1024 : 0) + (sks ? 1024 : 0));
        #pragma unroll
        for (int p = 0; p < 6; ++p) {
            v4i af = *(const v4i*)(base + p * 2048 + woh * 1024 + lane * 16);
            #pragma unroll
            for (int q = 0; q < 6; ++q) {
                if (p + q <= 5)
                    acc[p + q] = __builtin_amdgcn_mfma_i32_32x32x32_i8(
                        af, bf[q], acc[p + q], 0, 0, 0);
            }
        }
        __syncthreads();
    }

    // Runtime D-placement probes (R6/R7 technique).
    const int lr = lane & 31;
    const int rv = (lr + 1) * 0x01010101;
    const v4i pav  = {rv, rv, rv, rv};
    const v4i onev = {0x01010101, 0x01010101, 0x01010101, 0x01010101};
    const v16i z = (v16i){0,0,0,0,0,0,0,0,0,0,0,0,0,0,0,0};
    v16i d1 = __builtin_amdgcn_mfma_i32_32x32x32_i8(pav, onev, z, 0, 0, 0);
    v16i d2 = __builtin_amdgcn_mfma_i32_32x32x32_i8(onev, pav, z, 0, 0, 0);

    const int col = (d2[0] >> 5) - 1;            // 0..31 within tile
    const int gt = t0 + wth * 32 + col;
    const int eb = beta_e[b * T_DIM + gt];
    float* ohi = syn_hi + ((size_t)b * OUT_DIM + o0) * T_DIM + gt;
    float* olo = syn_lo + ((size_t)b * OUT_DIM + o0) * T_DIM + gt;

    const double C0 = 0x1p-14, C1 = 0x1p-21, C2 = 0x1p-28, C3 = 0x1p-35,
                 C4 = 0x1p-42, C5 = 0x1p-49;
    #pragma unroll
    for (int r = 0; r < 16; ++r) {
        const int row = (d1[r] >> 5) - 1;        // 0..31 within tile
        const int go = woh * 32 + row;
        const int ea = alpha_e[o0 + go];
        double v = (double)acc[0][r] * C0 + (double)acc[1][r] * C1 +
                   (double)acc[2][r] * C2 + (double)acc[3][r] * C3 +
                   (double)acc[4][r] * C4 + (double)acc[5][r] * C5;
        double syn = ldexp(v, ea + eb);
        float hi = (float)syn;
        float lo = (float)(syn - (double)hi);
        ohi[(size_t)go * T_DIM] = hi;
        olo[(size_t)go * T_DIM] = lo;
    }
}

// ---------------- Fallback GEMM: R6 f64-MFMA with probes (proven) ----------
#define BM 128
#define BN 128
#define BK 16
#define LDA 130

__global__ __launch_bounds__(256, 2) void spk_gemm_mfma64p_kernel(
    const float* __restrict__ x, const float* __restrict__ W,
    float* __restrict__ syn_hi, float* __restrict__ syn_lo)
{
    const int tid  = threadIdx.x;
    const int lane = tid & 63;
    const int wave = tid >> 6;
    const int tb = blockIdx.x, ob = blockIdx.y, b = blockIdx.z;

    __shared__ __align__(16) double As[BK][LDA];
    __shared__ __align__(16) double Bs[BK][LDA];

    const v4d zz = {0.0, 0.0, 0.0, 0.0};
    v4d d1 = __builtin_amdgcn_mfma_f64_16x16x4f64((double)lane, 1.0, zz, 0, 0, 0);
    v4d d2 = __builtin_amdgcn_mfma_f64_16x16x4f64(1.0, (double)lane, zz, 0, 0, 0);
    const bool a_h1 = (((int)d1[0] & 3) == 0);
    const bool b_h1 = (((int)d2[0] & 3) == 0);
    int drow[4];
    #pragma unroll
    for (int r = 0; r < 4; ++r) {
        const int v = (int)d1[r];
        drow[r] = (a_h1 ? (v - 96) >> 2 : (v - 6) >> 4) & 15;
    }
    const int am = a_h1 ? (lane & 15) : (lane >> 2);
    const int ak = a_h1 ? (lane >> 4) : (lane & 3);
    const int bn = b_h1 ? (lane & 15) : (lane >> 2);
    const int bk = b_h1 ? (lane >> 4) : (lane & 3);
    const int dcol = lane & 15;

    const int o0 = ob * BM, t0 = tb * BN;
    const float* Wp = W + (size_t)o0 * IN_DIM;
    const float* xp = x + (size_t)b * IN_DIM * T_DIM + t0;
    const int wo = (wave >> 1) * 64, wt = (wave & 1) * 64;

    v4d acc[4][4];
    #pragma unroll
    for (int i = 0; i < 4; ++i)
        #pragma unroll
        for (int j = 0; j < 4; ++j) acc[i][j] = zz;

    const int ar0 = tid / 4, ac = (tid % 4) * 4;
    const int bkr0 = tid / 32, btc = (tid % 32) * 4;

    float4 pa[2], pb[2];
    #pragma unroll
    for (int p = 0; p < 2; ++p) {
        pa[p] = *(const float4*)&Wp[(size_t)(ar0 + p * 64) * IN_DIM + ac];
        pb[p] = *(const float4*)&xp[(size_t)(bkr0 + p * 8) * T_DIM + btc];
    }

    for (int k0 = 0; k0 < IN_DIM; k0 += BK) {
        #pragma unroll
        for (int p = 0; p < 2; ++p) {
            const int r = ar0 + p * 64;
            As[ac + 0][r] = (double)pa[p].x; As[ac + 1][r] = (double)pa[p].y;
            As[ac + 2][r] = (double)pa[p].z; As[ac + 3][r] = (double)pa[p].w;
            const int kr = bkr0 + p * 8;
            Bs[kr][btc + 0] = (double)pb[p].x; Bs[kr][btc + 1] = (double)pb[p].y;
            Bs[kr][btc + 2] = (double)pb[p].z; Bs[kr][btc + 3] = (double)pb[p].w;
        }
        if (k0 + BK < IN_DIM) {
            #pragma unroll
            for (int p = 0; p < 2; ++p) {
                pa[p] = *(const float4*)&Wp[(size_t)(ar0 + p * 64) * IN_DIM + k0 + BK + ac];
                pb[p] = *(const float4*)&xp[(size_t)(bkr0 + p * 8 + k0 + BK) * T_DIM + btc];
            }
        }
        __syncthreads();
        #pragma unroll
        for (int kk = 0; kk < 4; ++kk) {
            const int kra = kk * 4 + ak, krb = kk * 4 + bk;
            double a[4], bb[4];
            #pragma unroll
            for (int i = 0; i < 4; ++i) a[i] = As[kra][wo + i * 16 + am];
            #pragma unroll
            for (int j = 0; j < 4; ++j) bb[j] = Bs[krb][wt + j * 16 + bn];
            #pragma unroll
            for (int i = 0; i < 4; ++i)
                #pragma unroll
                for (int j = 0; j < 4; ++j)
                    acc[i][j] = __builtin_amdgcn_mfma_f64_16x16x4f64(a[i], bb[j], acc[i][j], 0, 0, 0);
        }
        __syncthreads();
    }

    float* ohi = syn_hi + ((size_t)b * OUT_DIM + o0) * T_DIM + t0;
    float* olo = syn_lo + ((size_t)b * OUT_DIM + o0) * T_DIM + t0;
    #pragma unroll
    for (int i = 0; i < 4; ++i)
        #pragma unroll
        for (int j = 0; j < 4; ++j) {
            const int col = wt + j * 16 + dcol;
            #pragma unroll
            for (int r = 0; r < 4; ++r) {
                double s = acc[i][j][r];
                float hi = (float)s;
                float lo = (float)(s - (double)hi);
                const size_t off = (size_t)(wo + i * 16 + drow[r]) * T_DIM + col;
                ohi[off] = hi; olo[off] = lo;
            }
        }
}

// ---------------- scan: f64 LIF, in place over hi (proven) ----------------
__global__ __launch_bounds__(256) void spk_scan_f64_kernel(
    float* __restrict__ hi, const float* __restrict__ lo)
{
    const int TC = 16;
    __shared__ float thi[256][TC + 1];
    __shared__ float tlo[256][TC + 1];
    const int tid = threadIdx.x;
    const size_t row0 = (size_t)blockIdx.x * 256;

    double mem = 0.0;
    for (int t0 = 0; t0 < T_DIM; t0 += TC) {
        #pragma unroll
        for (int p = 0; p < 4; ++p) {
            int id = tid + p * 256;
            int r = id / 4, c = (id % 4) * 4;
            size_t g = (row0 + r) * T_DIM + t0 + c;
            float4 vh = *(const float4*)&hi[g];
            thi[r][c] = vh.x; thi[r][c+1] = vh.y; thi[r][c+2] = vh.z; thi[r][c+3] = vh.w;
            float4 vl = *(const float4*)&lo[g];
            tlo[r][c] = vl.x; tlo[r][c+1] = vl.y; tlo[r][c+2] = vl.z; tlo[r][c+3] = vl.w;
        }
        __syncthreads();
        float spk[TC];
        #pragma unroll
        for (int t = 0; t < TC; ++t) {
            double s = (double)thi[tid][t] + (double)tlo[tid][t];
            double reset = (mem > 1.0) ? 1.0 : 0.0;
            mem = 0.9 * mem + s - reset;
            spk[t] = ((mem - 1.0) > 0.0) ? 1.0f : 0.0f;
        }
        __syncthreads();
        #pragma unroll
        for (int t = 0; t < TC; ++t) thi[tid][t] = spk[t];
        __syncthreads();
        #pragma unroll
        for (int p = 0; p < 4; ++p) {
            int id = tid + p * 256;
            int r = id / 4, c = (id % 4) * 4;
            float4 v = make_float4(thi[r][c], thi[r][c+1], thi[r][c+2], thi[r][c+3]);
            *(float4*)&hi[(row0 + r) * T_DIM + t0 + c] = v;
        }
        __syncthreads();
    }
}

extern "C" void kernel_launch(void* const* d_in, const int* in_sizes, int n_in,
                              void* d_out, int out_size, void* d_ws, size_t ws_size,
                              hipStream_t stream)
{
    const float* x = (const float*)d_in[0];
    const float* W = (const float*)d_in[1];
    float* hi = (float*)d_out;
    char* ws = (char*)d_ws;
    float* lo = (float*)(ws + LO_OFF);

    if (ws_size >= WS_NEED) {
        signed char* wsl = (signed char*)(ws + WSL_OFF);
        signed char* xsl = (signed char*)(ws + XSL_OFF);
        int* alpha = (int*)(ws + AL_OFF);
        int* beta  = (int*)(ws + BE_OFF);
        float* part = (float*)(ws + PART_OFF);

        k_beta_part<<<dim3(16, B_DIM), dim3(256), 0, stream>>>(x, part);
        k_beta<<<dim3(B_DIM), dim3(256), 0, stream>>>(part, beta);
        k_slice_w<<<dim3(OUT_DIM), dim3(256), 0, stream>>>(W, wsl, alpha);
        k_slice_x<<<dim3(4, 16, B_DIM), dim3(256), 0, stream>>>(x, beta, xsl);
        k_oz_gemm<<<dim3(4, 16, B_DIM), dim3(256), 0, stream>>>(wsl, xsl, alpha, beta, hi, lo);
    } else {
        spk_gemm_mfma64p_kernel<<<dim3(2, 8, B_DIM), dim3(256), 0, stream>>>(x, W, hi, lo);
    }
    spk_scan_f64_kernel<<<dim3((B_DIM * OUT_DIM) / 256), dim3(256), 0, stream>>>(hi, lo);
}